// Round 4
// baseline (29.330 us; speedup 1.0000x reference)
//
#include <hip/hip_runtime.h>
#include <stdint.h>

enum { B_ = 32, K_ = 16, N_ = 256 };

// ws layout (rebuilt every launch):
//   [0x00000, 0x10000)  CVW : u32 cv[b*512 + r*64 + w]  C-bit words (byte j=4w..4w+3)
//   [0x10000, 0x20000)  CVT : u64 cvt[b*256 + n]        C bytes r-major (stage 2)
//   [0x20000, 0x20080)  ACC : int acc[32]
//   [0x20080, 0x20084)  CNT : int counter
#define CVW_OFF  0x00000
#define CVT_OFF  0x10000
#define ACC_OFF  0x20000
#define CNT_OFF  0x20080
#define WS_NEED  0x20084

#define M4 0x01010101u

__device__ __forceinline__ uint32_t pack4i(int4 v) {
    return (uint32_t)(v.x & 255) | ((uint32_t)(v.y & 255) << 8) |
           ((uint32_t)(v.z & 255) << 16) | ((uint32_t)(v.w & 255) << 24);
}

// ------------------------------ prep (tiny) --------------------------------
// blocks 0..31: C tables for b = bid (256 threads = j). block 32: zero acc/cnt.
__global__ __launch_bounds__(256) void gf_prepC(const int* __restrict__ s32,
                                                uint8_t* __restrict__ ws) {
    const int tid = threadIdx.x, bid = blockIdx.x;
    if (bid < 32) {
        __shared__ uint32_t cvb[8 * 64];  // [r][w] words, byte j%4
        const int b = bid, j = tid;
        uint32_t c = (uint32_t)s32[b * 256 + j] & 255u;
        uint32_t A = 0, Bw = 0;
#pragma unroll
        for (int u = 0; u < 4; ++u) {
            A |= c << (8 * u);
            c = ((c << 1) & 255u) ^ ((c >> 7) * 29u);
        }
#pragma unroll
        for (int u = 0; u < 4; ++u) {
            Bw |= c << (8 * u);
            c = ((c << 1) & 255u) ^ ((c >> 7) * 29u);
        }
        uint32_t by[8];
#pragma unroll
        for (int r = 0; r < 8; ++r) {
            uint32_t t = (A >> r) & M4;
            uint32_t lo = (t | (t >> 7) | (t >> 14) | (t >> 21)) & 15u;
            uint32_t u2 = (Bw >> r) & M4;
            uint32_t hi = (u2 | (u2 >> 7) | (u2 >> 14) | (u2 >> 21)) & 15u;
            by[r] = lo | (hi << 4);
        }
        uint2 ct;
        ct.x = by[0] | (by[1] << 8) | (by[2] << 16) | (by[3] << 24);
        ct.y = by[4] | (by[5] << 8) | (by[6] << 16) | (by[7] << 24);
        ((uint2*)(ws + CVT_OFF))[b * 256 + j] = ct;

        uint8_t* cb = (uint8_t*)cvb;
#pragma unroll
        for (int r = 0; r < 8; ++r) cb[r * 256 + j] = (uint8_t)by[r];
        __syncthreads();
        uint32_t* cw = (uint32_t*)(ws + CVW_OFF) + b * 512;
        cw[tid] = cvb[tid];
        cw[tid + 256] = cvb[tid + 256];
    } else {
        if (tid < 32) ((int*)(ws + ACC_OFF))[tid] = 0;
        if (tid == 32) *((int*)(ws + CNT_OFF)) = 0;
    }
}

// ------------------------------ main ---------------------------------------
// 256 blocks = (k = bid>>4, b-pair = bid&15), 512 threads = (n = tid&255,
// h = tid>>8 : j-half). P read raw per-thread (32 int4) and byte-packed in
// registers; C via wave-uniform (scalar) loads. Finish fused via last-block.
__global__ __launch_bounds__(512) void gf_main4(const int* __restrict__ m32,
                                                const int* __restrict__ P32,
                                                uint8_t* __restrict__ ws,
                                                int* __restrict__ dout) {
    __shared__ uint32_t xch[2][2][256];
    __shared__ uint32_t wr[8];
    __shared__ int isLast;

    const int k = blockIdx.x >> 4, bp = blockIdx.x & 15;
    const int tid = threadIdx.x;
    const int n = tid & 255;
    const int h = __builtin_amdgcn_readfirstlane(tid >> 8);  // wave-uniform

    // load + byte-pack this thread's 128 raw P values (its j-half of row n)
    const int4* pr = (const int4*)P32 + (size_t)(k * 256 + n) * 64 + h * 32;
    uint4 pwq[8];
#pragma unroll
    for (int g = 0; g < 8; ++g) {
        int4 a = pr[4 * g + 0], b = pr[4 * g + 1];
        int4 c = pr[4 * g + 2], d = pr[4 * g + 3];
        pwq[g].x = pack4i(a);
        pwq[g].y = pack4i(b);
        pwq[g].z = pack4i(c);
        pwq[g].w = pack4i(d);
    }

    const uint32_t* __restrict__ cvbase = (const uint32_t*)(ws + CVW_OFF);
#pragma unroll
    for (int bb = 0; bb < 2; ++bb) {
        const int b = bp * 2 + bb;
        const uint32_t* __restrict__ cv = cvbase + b * 512 + h * 32;
        uint32_t xr[8] = {0, 0, 0, 0, 0, 0, 0, 0};
#pragma unroll
        for (int g = 0; g < 8; ++g) {
#pragma unroll
            for (int r = 0; r < 8; ++r) {
                uint4 c4 = *(const uint4*)(cv + r * 64 + g * 4);
                uint32_t a = (c4.x & pwq[g].x) ^ (c4.y & pwq[g].y) ^
                             (c4.z & pwq[g].z) ^ (c4.w & pwq[g].w);
                xr[r] ^= a;
            }
        }
        uint32_t part = 0;
#pragma unroll
        for (int r = 0; r < 8; ++r) part |= (uint32_t)(__popc(xr[r]) & 1) << r;
        xch[bb][h][n] = part;
    }
    __syncthreads();

    // stage 2: thread (bb = tid>>8, n) : prod = mul(stP, s[b,n]) via CVT bytes
    const int bb2 = tid >> 8;
    const int b2 = bp * 2 + bb2;
    uint32_t stP = xch[bb2][0][n] ^ xch[bb2][1][n];
    uint2 ct = ((const uint2*)(ws + CVT_OFF))[b2 * 256 + n];
    uint32_t prod = 0;
#pragma unroll
    for (int r = 0; r < 4; ++r)
        prod |= (uint32_t)(__popc(stP & ((ct.x >> (8 * r)) & 255u)) & 1) << r;
#pragma unroll
    for (int r = 0; r < 4; ++r)
        prod |= (uint32_t)(__popc(stP & ((ct.y >> (8 * r)) & 255u)) & 1) << (r + 4);

    uint32_t acc = prod;
#pragma unroll
    for (int off = 1; off < 64; off <<= 1) acc ^= __shfl_xor(acc, off, 64);
    if ((tid & 63) == 0) wr[tid >> 6] = acc;
    __syncthreads();

    int* accb = (int*)(ws + ACC_OFF);
    int* cnt  = (int*)(ws + CNT_OFF);
    if (tid == 0) {
        const int b0 = bp * 2, b1 = bp * 2 + 1;
        int t0 = (int)(wr[0] ^ wr[1] ^ wr[2] ^ wr[3]) - m32[b0 * 16 + k];
        int t1 = (int)(wr[4] ^ wr[5] ^ wr[6] ^ wr[7]) - m32[b1 * 16 + k];
        atomicAdd(&accb[b0], t0);
        atomicAdd(&accb[b1], t1);
        __threadfence();
        int old = atomicAdd(cnt, 1);
        isLast = (old == 255) ? 1 : 0;
    }
    __syncthreads();
    if (isLast && tid < 32) {
        int v = atomicAdd(&accb[tid], 0);  // coherent read
        dout[tid] = max(1 - v, 0);
    }
}

// ------------------------- fallback (tiny ws) ------------------------------
__global__ void prep_zero(int* __restrict__ out) {
    if (threadIdx.x < B_) out[threadIdx.x] = 0;
}
#define LK(sw, pw)                                                  \
    v ^= tbl[(((sw) & 255u) << 8) | ((pw) & 255u)];                 \
    v ^= tbl[((sw) & 0xFF00u) | (((pw) >> 8) & 255u)];              \
    v ^= tbl[(((sw) >> 8) & 0xFF00u) | (((pw) >> 16) & 255u)];      \
    v ^= tbl[(((sw) >> 16) & 0xFF00u) | ((pw) >> 24)];
__global__ __launch_bounds__(256) void gf_main_fb(const int* __restrict__ m,
                                                  const int* __restrict__ s32,
                                                  const int* __restrict__ P32,
                                                  const int* __restrict__ t32,
                                                  int* __restrict__ out) {
    __shared__ uint8_t tbl[65536];
    __shared__ uint8_t sb[256];
    __shared__ uint32_t wred[4];
    const int b = blockIdx.x >> 4, k = blockIdx.x & 15, tid = threadIdx.x;
    for (int i = tid; i < 16384; i += 256) {
        int4 v = ((const int4*)t32)[i];
        ((uint32_t*)tbl)[i] = pack4i(v);
    }
    if (tid < 64) {
        int4 v = ((const int4*)s32)[b * 64 + tid];
        ((uint32_t*)sb)[tid] = pack4i(v);
    }
    __syncthreads();
    uint32_t v = 0;
    const uint32_t* sw32 = (const uint32_t*)sb;
    const int4* prow32 = (const int4*)(P32 + ((size_t)k * N_ + tid) * N_);
#pragma unroll 4
    for (int j0 = 0; j0 < 64; j0 += 4) {
        uint32_t p0 = pack4i(prow32[j0]), p1 = pack4i(prow32[j0 + 1]);
        uint32_t p2 = pack4i(prow32[j0 + 2]), p3 = pack4i(prow32[j0 + 3]);
        uint32_t w0 = sw32[j0], w1 = sw32[j0 + 1], w2 = sw32[j0 + 2], w3 = sw32[j0 + 3];
        LK(w0, p0) LK(w1, p1) LK(w2, p2) LK(w3, p3)
    }
    uint32_t wv = tbl[(v << 8) | (uint32_t)sb[tid]];
#pragma unroll
    for (int off = 1; off < 64; off <<= 1) wv ^= __shfl_xor(wv, off, 64);
    if ((tid & 63) == 0) wred[tid >> 6] = wv;
    __syncthreads();
    if (tid == 0) {
        uint32_t x = wred[0] ^ wred[1] ^ wred[2] ^ wred[3];
        atomicAdd(&out[b], (int)x - m[b * K_ + k]);
    }
}
__global__ void gf_finish(int* __restrict__ out) {
    if (threadIdx.x < B_) {
        int v = out[threadIdx.x];
        out[threadIdx.x] = max(1 - v, 0);
    }
}

extern "C" void kernel_launch(void* const* d_in, const int* in_sizes, int n_in,
                              void* d_out, int out_size, void* d_ws, size_t ws_size,
                              hipStream_t stream) {
    const int* m     = (const int*)d_in[0];
    const int* s     = (const int*)d_in[1];
    const int* P     = (const int*)d_in[2];
    const int* table = (const int*)d_in[3];
    int* out = (int*)d_out;

    if (ws_size >= (size_t)WS_NEED) {
        uint8_t* ws = (uint8_t*)d_ws;
        gf_prepC<<<33, 256, 0, stream>>>(s, ws);
        gf_main4<<<256, 512, 0, stream>>>(m, P, ws, out);
    } else {
        prep_zero<<<1, 64, 0, stream>>>(out);
        gf_main_fb<<<B_ * K_, 256, 0, stream>>>(m, s, P, table, out);
        gf_finish<<<1, 64, 0, stream>>>(out);
    }
}

// Round 5
// 15.472 us; speedup vs baseline: 1.8957x; 1.8957x over previous
//
#include <hip/hip_runtime.h>
#include <stdint.h>

enum { B_ = 32, K_ = 16, N_ = 256 };

// ws: [0, 2048) part[b*16+k] partial ints (overwritten fully every call)
#define WS_NEED 2048

#define M4 0x01010101u

__device__ __forceinline__ uint32_t pack4i(int4 v) {
    return (uint32_t)(v.x & 255) | ((uint32_t)(v.y & 255) << 8) |
           ((uint32_t)(v.z & 255) << 16) | ((uint32_t)(v.w & 255) << 24);
}

// ------------------------------ main ---------------------------------------
// 256 blocks: bid = bp*16 + k  (k = bid&15 -> bid%8 = k%8 -> same-k blocks on
// one XCD). 512 threads = (bb = tid>>8, n/j = tid&255).
// Phase A: C tables in LDS + per-thread stage-2 constants in regs.
// Phase B: coalesced stage of raw k-slice -> byte-packed, chunk-XOR-swizzled
//          64 KB LDS tile (write & read both at the inherent 8 acc/bank).
// Phase C: thread (bb,n): stP bits r = popc-parity of XOR-fold(Prow & C[r]);
//          stage 2 from own regs; wave XOR-reduce; plain store of partials.
__global__ __launch_bounds__(512) void gf_main5(const int* __restrict__ s32,
                                                const int* __restrict__ P32,
                                                int* __restrict__ part) {
    __shared__ uint32_t ptile[256 * 64];      // 64 KB packed P tile (swizzled)
    __shared__ __align__(16) uint8_t cvb[2][2048];  // [bb][r*256+j]
    __shared__ uint32_t wr[8];

    const int k = blockIdx.x & 15, bp = blockIdx.x >> 4;
    const int tid = threadIdx.x;
    const int bb = __builtin_amdgcn_readfirstlane(tid >> 8);  // wave-uniform
    const int j = tid & 255;

    // ---- Phase A: C for b = bp*2+bb, multiplier s[b,j] ----
    uint32_t c = (uint32_t)s32[(bp * 2 + bb) * 256 + j] & 255u;
    uint32_t A = 0, Bw = 0;
#pragma unroll
    for (int u = 0; u < 4; ++u) {
        A |= c << (8 * u);
        c = ((c << 1) & 255u) ^ ((c >> 7) * 29u);
    }
#pragma unroll
    for (int u = 0; u < 4; ++u) {
        Bw |= c << (8 * u);
        c = ((c << 1) & 255u) ^ ((c >> 7) * 29u);
    }
    uint32_t by[8];
#pragma unroll
    for (int r = 0; r < 8; ++r) {
        uint32_t t = (A >> r) & M4;
        uint32_t lo = (t | (t >> 7) | (t >> 14) | (t >> 21)) & 15u;
        uint32_t u2 = (Bw >> r) & M4;
        uint32_t hi = (u2 | (u2 >> 7) | (u2 >> 14) | (u2 >> 21)) & 15u;
        by[r] = lo | (hi << 4);
        cvb[bb][r * 256 + j] = (uint8_t)by[r];
    }
    const uint32_t ct0 = by[0] | (by[1] << 8) | (by[2] << 16) | (by[3] << 24);
    const uint32_t ct1 = by[4] | (by[5] << 8) | (by[6] << 16) | (by[7] << 24);

    // ---- Phase B: stage k-slice, packed + swizzled ----
    const int4* praw = (const int4*)P32 + (size_t)k * 16384;
#pragma unroll 8
    for (int it = 0; it < 32; ++it) {
        const int g = tid + 512 * it;          // raw int4 index, coalesced
        uint32_t w = pack4i(praw[g]);          // one packed word (4 j-bytes)
        const int n = g >> 6, ihi = (g >> 2) & 15, wq = g & 3;
        ptile[(n << 6) + (((ihi ^ (n & 15))) << 2) + wq] = w;
    }
    __syncthreads();

    // ---- Phase C: stage 1 (parity GEMM row n vs C[bb]) ----
    const int n = j;
    const uint4* cv4 = (const uint4*)cvb[bb];  // [r*16 + i]
    const uint32_t* prow = &ptile[n << 6];
    const int nx = n & 15;
    uint32_t xr0 = 0, xr1 = 0, xr2 = 0, xr3 = 0, xr4 = 0, xr5 = 0, xr6 = 0, xr7 = 0;
#pragma unroll 4
    for (int i = 0; i < 16; ++i) {
        uint4 p = *(const uint4*)(prow + ((i ^ nx) << 2));
#define CACC(xr, r)                                                        \
        {                                                                  \
            uint4 cc = cv4[r * 16 + i];                                    \
            xr ^= (cc.x & p.x) ^ (cc.y & p.y) ^ (cc.z & p.z) ^ (cc.w & p.w); \
        }
        CACC(xr0, 0) CACC(xr1, 1) CACC(xr2, 2) CACC(xr3, 3)
        CACC(xr4, 4) CACC(xr5, 5) CACC(xr6, 6) CACC(xr7, 7)
#undef CACC
    }
    uint32_t stP = (uint32_t)(__popc(xr0) & 1) | ((uint32_t)(__popc(xr1) & 1) << 1) |
                   ((uint32_t)(__popc(xr2) & 1) << 2) | ((uint32_t)(__popc(xr3) & 1) << 3) |
                   ((uint32_t)(__popc(xr4) & 1) << 4) | ((uint32_t)(__popc(xr5) & 1) << 5) |
                   ((uint32_t)(__popc(xr6) & 1) << 6) | ((uint32_t)(__popc(xr7) & 1) << 7);

    // ---- stage 2: prod = mul(stP, s[b,n]) via own ct regs ----
    uint32_t prod = 0;
#pragma unroll
    for (int r = 0; r < 4; ++r)
        prod |= (uint32_t)(__popc(stP & ((ct0 >> (8 * r)) & 255u)) & 1) << r;
#pragma unroll
    for (int r = 0; r < 4; ++r)
        prod |= (uint32_t)(__popc(stP & ((ct1 >> (8 * r)) & 255u)) & 1) << (r + 4);

    // ---- block reduce: XOR over 256 n's per bb ----
    uint32_t acc = prod;
#pragma unroll
    for (int off = 1; off < 64; off <<= 1) acc ^= __shfl_xor(acc, off, 64);
    if ((tid & 63) == 0) wr[tid >> 6] = acc;
    __syncthreads();
    if (tid == 0) {
        int p0 = (int)(wr[0] ^ wr[1] ^ wr[2] ^ wr[3]);
        int p1 = (int)(wr[4] ^ wr[5] ^ wr[6] ^ wr[7]);
        part[(bp * 2 + 0) * 16 + k] = p0;
        part[(bp * 2 + 1) * 16 + k] = p1;
    }
}

// ------------------------------ finish -------------------------------------
__global__ __launch_bounds__(512) void gf_fin(const int* __restrict__ part,
                                              const int* __restrict__ m32,
                                              int* __restrict__ dout) {
    __shared__ int sd[512];
    const int t = threadIdx.x;
    sd[t] = part[t] - m32[t];
    __syncthreads();
    if (t < 32) {
        int s = 0;
#pragma unroll
        for (int kk = 0; kk < 16; ++kk) s += sd[t * 16 + kk];
        dout[t] = max(1 - s, 0);
    }
}

// ------------------------- fallback (tiny ws) ------------------------------
__global__ void prep_zero(int* __restrict__ out) {
    if (threadIdx.x < B_) out[threadIdx.x] = 0;
}
#define LK(sw, pw)                                                  \
    v ^= tbl[(((sw) & 255u) << 8) | ((pw) & 255u)];                 \
    v ^= tbl[((sw) & 0xFF00u) | (((pw) >> 8) & 255u)];              \
    v ^= tbl[(((sw) >> 8) & 0xFF00u) | (((pw) >> 16) & 255u)];      \
    v ^= tbl[(((sw) >> 16) & 0xFF00u) | ((pw) >> 24)];
__global__ __launch_bounds__(256) void gf_main_fb(const int* __restrict__ m,
                                                  const int* __restrict__ s32,
                                                  const int* __restrict__ P32,
                                                  const int* __restrict__ t32,
                                                  int* __restrict__ out) {
    __shared__ uint8_t tbl[65536];
    __shared__ uint8_t sb[256];
    __shared__ uint32_t wred[4];
    const int b = blockIdx.x >> 4, k = blockIdx.x & 15, tid = threadIdx.x;
    for (int i = tid; i < 16384; i += 256) {
        int4 v = ((const int4*)t32)[i];
        ((uint32_t*)tbl)[i] = pack4i(v);
    }
    if (tid < 64) {
        int4 v = ((const int4*)s32)[b * 64 + tid];
        ((uint32_t*)sb)[tid] = pack4i(v);
    }
    __syncthreads();
    uint32_t v = 0;
    const uint32_t* sw32 = (const uint32_t*)sb;
    const int4* prow32 = (const int4*)(P32 + ((size_t)k * N_ + tid) * N_);
#pragma unroll 4
    for (int j0 = 0; j0 < 64; j0 += 4) {
        uint32_t p0 = pack4i(prow32[j0]), p1 = pack4i(prow32[j0 + 1]);
        uint32_t p2 = pack4i(prow32[j0 + 2]), p3 = pack4i(prow32[j0 + 3]);
        uint32_t w0 = sw32[j0], w1 = sw32[j0 + 1], w2 = sw32[j0 + 2], w3 = sw32[j0 + 3];
        LK(w0, p0) LK(w1, p1) LK(w2, p2) LK(w3, p3)
    }
    uint32_t wv = tbl[(v << 8) | (uint32_t)sb[tid]];
#pragma unroll
    for (int off = 1; off < 64; off <<= 1) wv ^= __shfl_xor(wv, off, 64);
    if ((tid & 63) == 0) wred[tid >> 6] = wv;
    __syncthreads();
    if (tid == 0) {
        uint32_t x = wred[0] ^ wred[1] ^ wred[2] ^ wred[3];
        atomicAdd(&out[b], (int)x - m[b * K_ + k]);
    }
}
__global__ void gf_finish_fb(int* __restrict__ out) {
    if (threadIdx.x < B_) {
        int v = out[threadIdx.x];
        out[threadIdx.x] = max(1 - v, 0);
    }
}

extern "C" void kernel_launch(void* const* d_in, const int* in_sizes, int n_in,
                              void* d_out, int out_size, void* d_ws, size_t ws_size,
                              hipStream_t stream) {
    const int* m     = (const int*)d_in[0];
    const int* s     = (const int*)d_in[1];
    const int* P     = (const int*)d_in[2];
    const int* table = (const int*)d_in[3];
    int* out = (int*)d_out;

    if (ws_size >= (size_t)WS_NEED) {
        int* part = (int*)d_ws;
        gf_main5<<<256, 512, 0, stream>>>(s, P, part);
        gf_fin<<<1, 512, 0, stream>>>(part, m, out);
    } else {
        prep_zero<<<1, 64, 0, stream>>>(out);
        gf_main_fb<<<B_ * K_, 256, 0, stream>>>(m, s, P, table, out);
        gf_finish_fb<<<1, 64, 0, stream>>>(out);
    }
}

// Round 6
// 13.661 us; speedup vs baseline: 2.1470x; 1.1325x over previous
//
#include <hip/hip_runtime.h>
#include <stdint.h>

enum { B_ = 32, K_ = 16, N_ = 256 };

// ws: [0, 4096) part[b*32 + k*2 + nh] partial ints (fully overwritten each call)
#define WS_NEED 4096

#define M4 0x01010101u

__device__ __forceinline__ uint32_t pack4i(int4 v) {
    return (uint32_t)(v.x & 255) | ((uint32_t)(v.y & 255) << 8) |
           ((uint32_t)(v.z & 255) << 16) | ((uint32_t)(v.w & 255) << 24);
}

// ------------------------------ main ---------------------------------------
// 256 blocks: bid = bq*32 + nh*16 + k  (k = bid&15, nh = (bid>>4)&1, bq = bid>>5).
//   Blocks sharing the same P chunk (k, nh) have equal bid mod 32 -> same XCD.
// Block covers b in [bq*4, bq*4+4), rows n in [nh*128, nh*128+128), all j.
// 512 threads.
// Phase A: C tables for 4 b's (each thread: j = tid&255, two bb's) -> LDS
//          bit-planes cvb[4][8*256] + stage-2 bytes ct_lds[4][256].
// Phase B: coalesced stage of the (k, nh) quarter-slice -> byte-packed,
//          chunk-XOR-swizzled 32 KB LDS tile.
// Phase C: thread = (bb = tid>>7, h = (tid>>6)&1, nl = tid&63): for rows
//          nl and nl+64, i in [8h,8h+8): xr[r] ^= fold(C[r][i] & Prow[i]);
//          C quads shared across the 2 rows. Partial bytes -> xch.
// Stage 2: thread (bb, nl128): stP = xch[bb][0]^xch[bb][1]; prod via ct_lds;
//          wave XOR-reduce -> part[(bq*4+bb)*32 + k*2 + nh].
__global__ __launch_bounds__(512) void gf_main6(const int* __restrict__ s32,
                                                const int* __restrict__ P32,
                                                int* __restrict__ part) {
    __shared__ uint32_t ptile[128 * 64];            // 32 KB packed P (swizzled)
    __shared__ __align__(16) uint8_t cvb[4][2048];  // [bb][r*256+j] bit-planes
    __shared__ uint2 ct_lds[4][256];                // [bb][j] stage-2 bytes
    __shared__ uint32_t xch[4][2][128];             // [bb][h][row] partials
    __shared__ uint32_t wr[8];

    const int bid = blockIdx.x;
    const int k = bid & 15, nh = (bid >> 4) & 1, bq = bid >> 5;
    const int tid = threadIdx.x;

    // ---- Phase A: C tables for the block's 4 b's ----
    {
        const int j = tid & 255;
#pragma unroll
        for (int e = 0; e < 2; ++e) {
            const int bbx = (tid >> 8) + 2 * e;
            uint32_t c = (uint32_t)s32[(bq * 4 + bbx) * 256 + j] & 255u;
            uint32_t A = 0, Bw = 0;
#pragma unroll
            for (int u = 0; u < 4; ++u) {
                A |= c << (8 * u);
                c = ((c << 1) & 255u) ^ ((c >> 7) * 29u);
            }
#pragma unroll
            for (int u = 0; u < 4; ++u) {
                Bw |= c << (8 * u);
                c = ((c << 1) & 255u) ^ ((c >> 7) * 29u);
            }
            uint32_t by[8];
#pragma unroll
            for (int r = 0; r < 8; ++r) {
                uint32_t t = (A >> r) & M4;
                uint32_t lo = (t | (t >> 7) | (t >> 14) | (t >> 21)) & 15u;
                uint32_t u2 = (Bw >> r) & M4;
                uint32_t hi = (u2 | (u2 >> 7) | (u2 >> 14) | (u2 >> 21)) & 15u;
                by[r] = lo | (hi << 4);
                cvb[bbx][r * 256 + j] = (uint8_t)by[r];
            }
            uint2 ct;
            ct.x = by[0] | (by[1] << 8) | (by[2] << 16) | (by[3] << 24);
            ct.y = by[4] | (by[5] << 8) | (by[6] << 16) | (by[7] << 24);
            ct_lds[bbx][j] = ct;
        }
    }

    // ---- Phase B: stage the (k, nh) quarter-slice, packed + swizzled ----
    const int4* praw = (const int4*)P32 + (size_t)k * 16384 + nh * 8192;
#pragma unroll 8
    for (int it = 0; it < 16; ++it) {
        const int g = tid + 512 * it;          // raw int4 index, coalesced
        uint32_t w = pack4i(praw[g]);
        const int n = g >> 6, ihi = (g >> 2) & 15, wq = g & 3;
        ptile[(n << 6) + ((ihi ^ (n & 15)) << 2) + wq] = w;
    }
    __syncthreads();

    // ---- Phase C: stage 1, i-half split, 2 rows per thread ----
    {
        const int bh = __builtin_amdgcn_readfirstlane(tid >> 6);  // wave-uniform
        const int bb = bh >> 1, h = bh & 1;
        const int nl = tid & 63;
        const int nx = nl & 15;                 // (nl+64)&15 == nx
        const uint4* cvq = (const uint4*)cvb[bb];
        const uint32_t* prow0 = &ptile[nl << 6];
        const uint32_t* prow1 = &ptile[(nl + 64) << 6];
        uint32_t xa0 = 0, xa1 = 0, xa2 = 0, xa3 = 0, xa4 = 0, xa5 = 0, xa6 = 0, xa7 = 0;
        uint32_t xb0 = 0, xb1 = 0, xb2 = 0, xb3 = 0, xb4 = 0, xb5 = 0, xb6 = 0, xb7 = 0;
#pragma unroll 4
        for (int ii = 0; ii < 8; ++ii) {
            const int i = 8 * h + ii;
            const int slot = (i ^ nx) << 2;
            uint4 p0 = *(const uint4*)(prow0 + slot);
            uint4 p1 = *(const uint4*)(prow1 + slot);
#define CACC(xa, xb, r)                                                       \
            {                                                                 \
                uint4 cc = cvq[(r) * 16 + i];                                 \
                xa ^= (cc.x & p0.x) ^ (cc.y & p0.y) ^ (cc.z & p0.z) ^ (cc.w & p0.w); \
                xb ^= (cc.x & p1.x) ^ (cc.y & p1.y) ^ (cc.z & p1.z) ^ (cc.w & p1.w); \
            }
            CACC(xa0, xb0, 0) CACC(xa1, xb1, 1) CACC(xa2, xb2, 2) CACC(xa3, xb3, 3)
            CACC(xa4, xb4, 4) CACC(xa5, xb5, 5) CACC(xa6, xb6, 6) CACC(xa7, xb7, 7)
#undef CACC
        }
        uint32_t pa = (uint32_t)(__popc(xa0) & 1) | ((uint32_t)(__popc(xa1) & 1) << 1) |
                      ((uint32_t)(__popc(xa2) & 1) << 2) | ((uint32_t)(__popc(xa3) & 1) << 3) |
                      ((uint32_t)(__popc(xa4) & 1) << 4) | ((uint32_t)(__popc(xa5) & 1) << 5) |
                      ((uint32_t)(__popc(xa6) & 1) << 6) | ((uint32_t)(__popc(xa7) & 1) << 7);
        uint32_t pb = (uint32_t)(__popc(xb0) & 1) | ((uint32_t)(__popc(xb1) & 1) << 1) |
                      ((uint32_t)(__popc(xb2) & 1) << 2) | ((uint32_t)(__popc(xb3) & 1) << 3) |
                      ((uint32_t)(__popc(xb4) & 1) << 4) | ((uint32_t)(__popc(xb5) & 1) << 5) |
                      ((uint32_t)(__popc(xb6) & 1) << 6) | ((uint32_t)(__popc(xb7) & 1) << 7);
        xch[bb][h][nl] = pa;
        xch[bb][h][nl + 64] = pb;
    }
    __syncthreads();

    // ---- Stage 2 + reduce ----
    {
        const int bb = tid >> 7, nl = tid & 127;
        uint32_t stP = xch[bb][0][nl] ^ xch[bb][1][nl];
        uint2 ct = ct_lds[bb][nh * 128 + nl];
        uint32_t prod = 0;
#pragma unroll
        for (int r = 0; r < 4; ++r)
            prod |= (uint32_t)(__popc(stP & ((ct.x >> (8 * r)) & 255u)) & 1) << r;
#pragma unroll
        for (int r = 0; r < 4; ++r)
            prod |= (uint32_t)(__popc(stP & ((ct.y >> (8 * r)) & 255u)) & 1) << (r + 4);

        uint32_t acc = prod;
#pragma unroll
        for (int off = 1; off < 64; off <<= 1) acc ^= __shfl_xor(acc, off, 64);
        if ((tid & 63) == 0) wr[tid >> 6] = acc;
    }
    __syncthreads();
    if (tid == 0) {
#pragma unroll
        for (int bb = 0; bb < 4; ++bb) {
            int pv = (int)(wr[2 * bb] ^ wr[2 * bb + 1]);
            part[(bq * 4 + bb) * 32 + k * 2 + nh] = pv;
        }
    }
}

// ------------------------------ finish -------------------------------------
__global__ __launch_bounds__(512) void gf_fin(const int* __restrict__ part,
                                              const int* __restrict__ m32,
                                              int* __restrict__ dout) {
    __shared__ int sd[512];
    const int t = threadIdx.x;
    sd[t] = (int)(((const uint32_t*)part)[2 * t] ^ ((const uint32_t*)part)[2 * t + 1]) - m32[t];
    __syncthreads();
    if (t < 32) {
        int s = 0;
#pragma unroll
        for (int kk = 0; kk < 16; ++kk) s += sd[t * 16 + kk];
        dout[t] = max(1 - s, 0);
    }
}

// ------------------------- fallback (tiny ws) ------------------------------
__global__ void prep_zero(int* __restrict__ out) {
    if (threadIdx.x < B_) out[threadIdx.x] = 0;
}
#define LK(sw, pw)                                                  \
    v ^= tbl[(((sw) & 255u) << 8) | ((pw) & 255u)];                 \
    v ^= tbl[((sw) & 0xFF00u) | (((pw) >> 8) & 255u)];              \
    v ^= tbl[(((sw) >> 8) & 0xFF00u) | (((pw) >> 16) & 255u)];      \
    v ^= tbl[(((sw) >> 16) & 0xFF00u) | ((pw) >> 24)];
__global__ __launch_bounds__(256) void gf_main_fb(const int* __restrict__ m,
                                                  const int* __restrict__ s32,
                                                  const int* __restrict__ P32,
                                                  const int* __restrict__ t32,
                                                  int* __restrict__ out) {
    __shared__ uint8_t tbl[65536];
    __shared__ uint8_t sb[256];
    __shared__ uint32_t wred[4];
    const int b = blockIdx.x >> 4, k = blockIdx.x & 15, tid = threadIdx.x;
    for (int i = tid; i < 16384; i += 256) {
        int4 v = ((const int4*)t32)[i];
        ((uint32_t*)tbl)[i] = pack4i(v);
    }
    if (tid < 64) {
        int4 v = ((const int4*)s32)[b * 64 + tid];
        ((uint32_t*)sb)[tid] = pack4i(v);
    }
    __syncthreads();
    uint32_t v = 0;
    const uint32_t* sw32 = (const uint32_t*)sb;
    const int4* prow32 = (const int4*)(P32 + ((size_t)k * N_ + tid) * N_);
#pragma unroll 4
    for (int j0 = 0; j0 < 64; j0 += 4) {
        uint32_t p0 = pack4i(prow32[j0]), p1 = pack4i(prow32[j0 + 1]);
        uint32_t p2 = pack4i(prow32[j0 + 2]), p3 = pack4i(prow32[j0 + 3]);
        uint32_t w0 = sw32[j0], w1 = sw32[j0 + 1], w2 = sw32[j0 + 2], w3 = sw32[j0 + 3];
        LK(w0, p0) LK(w1, p1) LK(w2, p2) LK(w3, p3)
    }
    uint32_t wv = tbl[(v << 8) | (uint32_t)sb[tid]];
#pragma unroll
    for (int off = 1; off < 64; off <<= 1) wv ^= __shfl_xor(wv, off, 64);
    if ((tid & 63) == 0) wred[tid >> 6] = wv;
    __syncthreads();
    if (tid == 0) {
        uint32_t x = wred[0] ^ wred[1] ^ wred[2] ^ wred[3];
        atomicAdd(&out[b], (int)x - m[b * K_ + k]);
    }
}
__global__ void gf_finish_fb(int* __restrict__ out) {
    if (threadIdx.x < B_) {
        int v = out[threadIdx.x];
        out[threadIdx.x] = max(1 - v, 0);
    }
}

extern "C" void kernel_launch(void* const* d_in, const int* in_sizes, int n_in,
                              void* d_out, int out_size, void* d_ws, size_t ws_size,
                              hipStream_t stream) {
    const int* m     = (const int*)d_in[0];
    const int* s     = (const int*)d_in[1];
    const int* P     = (const int*)d_in[2];
    const int* table = (const int*)d_in[3];
    int* out = (int*)d_out;

    if (ws_size >= (size_t)WS_NEED) {
        int* part = (int*)d_ws;
        gf_main6<<<256, 512, 0, stream>>>(s, P, part);
        gf_fin<<<1, 512, 0, stream>>>(part, m, out);
    } else {
        prep_zero<<<1, 64, 0, stream>>>(out);
        gf_main_fb<<<B_ * K_, 256, 0, stream>>>(m, s, P, table, out);
        gf_finish_fb<<<1, 64, 0, stream>>>(out);
    }
}

// Round 7
// 13.478 us; speedup vs baseline: 2.1761x; 1.0136x over previous
//
#include <hip/hip_runtime.h>
#include <stdint.h>

enum { B_ = 32, K_ = 16, N_ = 256 };

// ws: [0, 4096) part[b*32 + k*2 + nh] partial ints (fully overwritten each call)
#define WS_NEED 4096

#define M4 0x01010101u

__device__ __forceinline__ uint32_t pack4i(int4 v) {
    return (uint32_t)(v.x & 255) | ((uint32_t)(v.y & 255) << 8) |
           ((uint32_t)(v.z & 255) << 16) | ((uint32_t)(v.w & 255) << 24);
}

#if __has_builtin(__builtin_amdgcn_perm)
__device__ __forceinline__ uint32_t pack4p(uint4 v) {
    uint32_t lo = __builtin_amdgcn_perm(v.y, v.x, 0x0C0C0400u);  // [x0,y0,0,0]
    uint32_t hi = __builtin_amdgcn_perm(v.w, v.z, 0x04000C0Cu);  // [0,0,z0,w0]
    return lo | hi;
}
#else
__device__ __forceinline__ uint32_t pack4p(uint4 v) {
    return (v.x & 255u) | ((v.y & 255u) << 8) | ((v.z & 255u) << 16) | ((v.w & 255u) << 24);
}
#endif

// ------------------------------ main ---------------------------------------
// 256 blocks: bid = bq*32 + nh*16 + k. Block covers b in [bq*4,bq*4+4),
// rows n in [nh*128, nh*128+128), all j. 512 threads.
// Phase B loads issued FIRST (hide L2 latency under phase A VALU).
// Phase A: C tables for 4 b's -> cvb bit-planes + ct_lds stage-2 bytes.
// Phase B: pack (v_perm) + swizzled 32 KB LDS tile write.
// Phase C: thread = (bb = tid>>7, iq = (tid>>5)&3, nl = tid&31) covers rows
//          {nl, nl+32, nl+64, nl+96} x i-chunks [iq*4, iq*4+4): each C quad
//          read once, used for 4 rows. Partial bytes -> xch[bb][iq][row].
// Stage 2: thread (bb, n2): stP = XOR of 4 iq partials; prod via ct_lds;
//          wave XOR-reduce -> part.
__global__ __launch_bounds__(512) void gf_main7(const int* __restrict__ s32,
                                                const int* __restrict__ P32,
                                                int* __restrict__ part) {
    __shared__ uint32_t ptile[128 * 64];            // 32 KB packed P (swizzled)
    __shared__ __align__(16) uint8_t cvb[4][2048];  // [bb][r*256+j] bit-planes
    __shared__ uint2 ct_lds[4][256];                // [bb][j] stage-2 bytes
    __shared__ uint32_t xch[4 * 4 * 128];           // [bb][iq][row] partials
    __shared__ uint32_t wr[8];

    const int bid = blockIdx.x;
    const int k = bid & 15, nh = (bid >> 4) & 1, bq = bid >> 5;
    const int tid = threadIdx.x;

    // ---- Phase B loads issued early ----
    const uint4* praw = (const uint4*)P32 + (size_t)k * 16384 + (size_t)nh * 8192;
    uint4 pr_[16];
#pragma unroll
    for (int it = 0; it < 16; ++it) pr_[it] = praw[tid + 512 * it];

    // ---- Phase A: C tables for the block's 4 b's ----
    {
        const int j = tid & 255;
#pragma unroll
        for (int e = 0; e < 2; ++e) {
            const int bbx = (tid >> 8) + 2 * e;
            uint32_t c = (uint32_t)s32[(bq * 4 + bbx) * 256 + j] & 255u;
            uint32_t A = 0, Bw = 0;
#pragma unroll
            for (int u = 0; u < 4; ++u) {
                A |= c << (8 * u);
                c = ((c << 1) & 255u) ^ ((c >> 7) * 29u);
            }
#pragma unroll
            for (int u = 0; u < 4; ++u) {
                Bw |= c << (8 * u);
                c = ((c << 1) & 255u) ^ ((c >> 7) * 29u);
            }
            uint32_t by[8];
#pragma unroll
            for (int r = 0; r < 8; ++r) {
                uint32_t t = (A >> r) & M4;
                uint32_t lo = (t | (t >> 7) | (t >> 14) | (t >> 21)) & 15u;
                uint32_t u2 = (Bw >> r) & M4;
                uint32_t hi = (u2 | (u2 >> 7) | (u2 >> 14) | (u2 >> 21)) & 15u;
                by[r] = lo | (hi << 4);
                cvb[bbx][r * 256 + j] = (uint8_t)by[r];
            }
            uint2 ct;
            ct.x = by[0] | (by[1] << 8) | (by[2] << 16) | (by[3] << 24);
            ct.y = by[4] | (by[5] << 8) | (by[6] << 16) | (by[7] << 24);
            ct_lds[bbx][j] = ct;
        }
    }

    // ---- Phase B: pack + swizzled tile write ----
#pragma unroll
    for (int it = 0; it < 16; ++it) {
        const int g = tid + 512 * it;
        uint32_t w = pack4p(pr_[it]);
        const int n = g >> 6, ihi = (g >> 2) & 15, wq = g & 3;
        ptile[(n << 6) + ((ihi ^ (n & 15)) << 2) + wq] = w;
    }
    __syncthreads();

    // ---- Phase C: 4 rows x 4 i-chunks per thread ----
    {
        const int bb = __builtin_amdgcn_readfirstlane(tid >> 7);  // wave-uniform
        const int iq = (tid >> 5) & 3;                            // half-wave uniform
        const int nl = tid & 31;
        const int nx = nl & 15;  // same for rows nl+32m
        const uint4* cvq = (const uint4*)cvb[bb];
        const uint32_t* prow0 = &ptile[nl << 6];
        const uint32_t* prow1 = &ptile[(nl + 32) << 6];
        const uint32_t* prow2 = &ptile[(nl + 64) << 6];
        const uint32_t* prow3 = &ptile[(nl + 96) << 6];

        uint32_t x0_[8] = {0,0,0,0,0,0,0,0};
        uint32_t x1_[8] = {0,0,0,0,0,0,0,0};
        uint32_t x2_[8] = {0,0,0,0,0,0,0,0};
        uint32_t x3_[8] = {0,0,0,0,0,0,0,0};
#pragma unroll
        for (int ii = 0; ii < 4; ++ii) {
            const int i = iq * 4 + ii;
            const int slot = (i ^ nx) << 2;
            uint4 p0 = *(const uint4*)(prow0 + slot);
            uint4 p1 = *(const uint4*)(prow1 + slot);
            uint4 p2 = *(const uint4*)(prow2 + slot);
            uint4 p3 = *(const uint4*)(prow3 + slot);
#pragma unroll
            for (int r = 0; r < 8; ++r) {
                uint4 cc = cvq[r * 16 + i];
                x0_[r] ^= (cc.x & p0.x) ^ (cc.y & p0.y) ^ (cc.z & p0.z) ^ (cc.w & p0.w);
                x1_[r] ^= (cc.x & p1.x) ^ (cc.y & p1.y) ^ (cc.z & p1.z) ^ (cc.w & p1.w);
                x2_[r] ^= (cc.x & p2.x) ^ (cc.y & p2.y) ^ (cc.z & p2.z) ^ (cc.w & p2.w);
                x3_[r] ^= (cc.x & p3.x) ^ (cc.y & p3.y) ^ (cc.z & p3.z) ^ (cc.w & p3.w);
            }
        }
        const int xb = ((bb * 4 + iq) << 7) + nl;
        uint32_t pb;
#define EMIT(xa, rr)                                                           \
        pb = (uint32_t)(__popc(xa[0]) & 1)        | ((uint32_t)(__popc(xa[1]) & 1) << 1) | \
             ((uint32_t)(__popc(xa[2]) & 1) << 2) | ((uint32_t)(__popc(xa[3]) & 1) << 3) | \
             ((uint32_t)(__popc(xa[4]) & 1) << 4) | ((uint32_t)(__popc(xa[5]) & 1) << 5) | \
             ((uint32_t)(__popc(xa[6]) & 1) << 6) | ((uint32_t)(__popc(xa[7]) & 1) << 7); \
        xch[xb + 32 * rr] = pb;
        EMIT(x0_, 0) EMIT(x1_, 1) EMIT(x2_, 2) EMIT(x3_, 3)
#undef EMIT
    }
    __syncthreads();

    // ---- Stage 2 + reduce ----
    {
        const int bb = tid >> 7, n2 = tid & 127;
        uint32_t stP = xch[(bb * 4 + 0) * 128 + n2] ^ xch[(bb * 4 + 1) * 128 + n2] ^
                       xch[(bb * 4 + 2) * 128 + n2] ^ xch[(bb * 4 + 3) * 128 + n2];
        uint2 ct = ct_lds[bb][nh * 128 + n2];
        uint32_t prod = 0;
#pragma unroll
        for (int r = 0; r < 4; ++r)
            prod |= (uint32_t)(__popc(stP & ((ct.x >> (8 * r)) & 255u)) & 1) << r;
#pragma unroll
        for (int r = 0; r < 4; ++r)
            prod |= (uint32_t)(__popc(stP & ((ct.y >> (8 * r)) & 255u)) & 1) << (r + 4);

        uint32_t acc = prod;
#pragma unroll
        for (int off = 1; off < 64; off <<= 1) acc ^= __shfl_xor(acc, off, 64);
        if ((tid & 63) == 0) wr[tid >> 6] = acc;
    }
    __syncthreads();
    if (tid == 0) {
#pragma unroll
        for (int bb = 0; bb < 4; ++bb) {
            int pv = (int)(wr[2 * bb] ^ wr[2 * bb + 1]);
            part[(bq * 4 + bb) * 32 + k * 2 + nh] = pv;
        }
    }
}

// ------------------------------ finish -------------------------------------
__global__ __launch_bounds__(512) void gf_fin(const int* __restrict__ part,
                                              const int* __restrict__ m32,
                                              int* __restrict__ dout) {
    __shared__ int sd[512];
    const int t = threadIdx.x;
    sd[t] = (int)(((const uint32_t*)part)[2 * t] ^ ((const uint32_t*)part)[2 * t + 1]) - m32[t];
    __syncthreads();
    if (t < 32) {
        int s = 0;
#pragma unroll
        for (int kk = 0; kk < 16; ++kk) s += sd[t * 16 + kk];
        dout[t] = max(1 - s, 0);
    }
}

// ------------------------- fallback (tiny ws) ------------------------------
__global__ void prep_zero(int* __restrict__ out) {
    if (threadIdx.x < B_) out[threadIdx.x] = 0;
}
#define LK(sw, pw)                                                  \
    v ^= tbl[(((sw) & 255u) << 8) | ((pw) & 255u)];                 \
    v ^= tbl[((sw) & 0xFF00u) | (((pw) >> 8) & 255u)];              \
    v ^= tbl[(((sw) >> 8) & 0xFF00u) | (((pw) >> 16) & 255u)];      \
    v ^= tbl[(((sw) >> 16) & 0xFF00u) | ((pw) >> 24)];
__global__ __launch_bounds__(256) void gf_main_fb(const int* __restrict__ m,
                                                  const int* __restrict__ s32,
                                                  const int* __restrict__ P32,
                                                  const int* __restrict__ t32,
                                                  int* __restrict__ out) {
    __shared__ uint8_t tbl[65536];
    __shared__ uint8_t sb[256];
    __shared__ uint32_t wred[4];
    const int b = blockIdx.x >> 4, k = blockIdx.x & 15, tid = threadIdx.x;
    for (int i = tid; i < 16384; i += 256) {
        int4 v = ((const int4*)t32)[i];
        ((uint32_t*)tbl)[i] = pack4i(v);
    }
    if (tid < 64) {
        int4 v = ((const int4*)s32)[b * 64 + tid];
        ((uint32_t*)sb)[tid] = pack4i(v);
    }
    __syncthreads();
    uint32_t v = 0;
    const uint32_t* sw32 = (const uint32_t*)sb;
    const int4* prow32 = (const int4*)(P32 + ((size_t)k * N_ + tid) * N_);
#pragma unroll 4
    for (int j0 = 0; j0 < 64; j0 += 4) {
        uint32_t p0 = pack4i(prow32[j0]), p1 = pack4i(prow32[j0 + 1]);
        uint32_t p2 = pack4i(prow32[j0 + 2]), p3 = pack4i(prow32[j0 + 3]);
        uint32_t w0 = sw32[j0], w1 = sw32[j0 + 1], w2 = sw32[j0 + 2], w3 = sw32[j0 + 3];
        LK(w0, p0) LK(w1, p1) LK(w2, p2) LK(w3, p3)
    }
    uint32_t wv = tbl[(v << 8) | (uint32_t)sb[tid]];
#pragma unroll
    for (int off = 1; off < 64; off <<= 1) wv ^= __shfl_xor(wv, off, 64);
    if ((tid & 63) == 0) wred[tid >> 6] = wv;
    __syncthreads();
    if (tid == 0) {
        uint32_t x = wred[0] ^ wred[1] ^ wred[2] ^ wred[3];
        atomicAdd(&out[b], (int)x - m[b * K_ + k]);
    }
}
__global__ void gf_finish_fb(int* __restrict__ out) {
    if (threadIdx.x < B_) {
        int v = out[threadIdx.x];
        out[threadIdx.x] = max(1 - v, 0);
    }
}

extern "C" void kernel_launch(void* const* d_in, const int* in_sizes, int n_in,
                              void* d_out, int out_size, void* d_ws, size_t ws_size,
                              hipStream_t stream) {
    const int* m     = (const int*)d_in[0];
    const int* s     = (const int*)d_in[1];
    const int* P     = (const int*)d_in[2];
    const int* table = (const int*)d_in[3];
    int* out = (int*)d_out;

    if (ws_size >= (size_t)WS_NEED) {
        int* part = (int*)d_ws;
        gf_main7<<<256, 512, 0, stream>>>(s, P, part);
        gf_fin<<<1, 512, 0, stream>>>(part, m, out);
    } else {
        prep_zero<<<1, 64, 0, stream>>>(out);
        gf_main_fb<<<B_ * K_, 256, 0, stream>>>(m, s, P, table, out);
        gf_finish_fb<<<1, 64, 0, stream>>>(out);
    }
}